// Round 16
// baseline (196.832 us; speedup 1.0000x reference)
//
#include <hip/hip_runtime.h>
#include <hip/hip_fp16.h>

#define NDIM 8192
#define KDIM 8192
#define NT 256          // N / 32 hash tiles
#define MOD2 4193281    // HASH_SIZE - 32*32 + 1
#define PRIME 2038074743LL

#define BM 256
#define BN 128
#define BK 32
#define KITER 64        // (KDIM/4)/BK, split-K = 4
#define BSLAB 1032      // halves per k-octet slab (128*8 + 8 pad; phase-balanced)

typedef _Float16 half8 __attribute__((ext_vector_type(8)));
typedef float floatx4 __attribute__((ext_vector_type(4)));

// ---------------- fused prepass: cvt fp32->f16, out=bias, ROBE-Z starts ----------------
__global__ __launch_bounds__(256) void prep_kernel(const float* __restrict__ x,
                                                   const float* __restrict__ hw,
                                                   const float* __restrict__ bias,
                                                   const int* __restrict__ rn,
                                                   __half* __restrict__ xh,
                                                   __half* __restrict__ hh,
                                                   int* __restrict__ starts,
                                                   float* __restrict__ out) {
    int b = blockIdx.x;
    int tid = threadIdx.x;
    if (b < 8192) {                       // cvt: 2M threads x 4 floats
        int i = b * 256 + tid;
        const float4* s; __half2* d; int j;
        if (i < (1 << 20)) { s = (const float4*)x;  d = (__half2*)xh; j = i; }
        else               { s = (const float4*)hw; d = (__half2*)hh; j = i - (1 << 20); }
        float4 v = s[j];
        d[j * 2]     = __floats2half2_rn(v.x, v.y);
        d[j * 2 + 1] = __floats2half2_rn(v.z, v.w);
    } else if (b < 8192 + 4096) {         // init: out = bias (atomic targets)
        int i = (b - 8192) * 256 + tid;
        float4 bv = *(const float4*)(bias + ((i & 2047) << 2));
        ((float4*)out)[i] = bv;
    } else {                              // starts: 64K hash tile offsets
        int t = (b - 12288) * 256 + tid;
        bool is64 = (rn[1] == 0 && rn[3] == 0);   // int64 input: words 1,3 are hi-halves
        long long R1 = is64 ? rn[2] : rn[1];
        long long R2 = is64 ? rn[4] : rn[2];
        long long R3 = is64 ? rn[6] : rn[3];
        long long k_id = t >> 8, n_id = t & 255;
        long long v = (k_id * R3 + n_id * R2 + R1) % PRIME;
        starts[t] = (int)(v % MOD2);
    }
}

// async global->LDS, 16B per lane; LDS dest = wave-uniform base + lane*16 (HW)
__device__ __forceinline__ void gload16(const __half* g, __half* l) {
    __builtin_amdgcn_global_load_lds((const __attribute__((address_space(1))) void*)g,
                                     (__attribute__((address_space(3))) void*)l, 16, 0, 0);
}

#define SBAR() __builtin_amdgcn_sched_barrier(0)
#define WAIT_LGKM0() __builtin_amdgcn_s_waitcnt(0xC07F)   // lgkmcnt(0) only

// ---------------- main GEMM: split-K=4, 256x128 block, 1-barrier-per-tile pipeline ----
// R12's data path (112.5us) with the sync cost halved: 3 rotating LDS buffers +
// dist-3 B loads give every producer->consumer pair >=2 barriers of separation,
// so ONE lgkm0+barrier per K-tile suffices (was rendezvous + counted-drain pair).
// Buffer index = tile%3, made STATIC via period-6 unroll (avoids R14's rotation
// VALU tax). Tile t: LOADT@t-3 -> STORET@t-2 -> READF@t; STAGE_A@t-2.
// Steady-state vm ordering is entirely via STORET's implicit register-wait
// (vmcnt(6)); only the tail (p62) needs an explicit vmcnt(0) [R11 lesson].
__global__ __launch_bounds__(512, 4) void gemm_kernel(
    const __half* __restrict__ xh, const __half* __restrict__ hh,
    const int* __restrict__ starts, float* __restrict__ out) {
    __shared__ __align__(16) __half As[3][BM * 32];        // 48 KB : [m][k] swizzled chunks
    __shared__ __align__(16) __half Bs[3][4 * BSLAB];      // 24.2 KB : [k-oct][n][8] swizzled
    __shared__ int Ss[KITER * 4];                          // 1 KB   (total 73.2 KB)

    const int tid = threadIdx.x;
    const int lane = tid & 63;
    const int wave = tid >> 6;       // 0..7
    const int wm = wave >> 1;        // 0..3 : 64-row strip
    const int wn = wave & 1;         // 0..1 : 64-col strip
    const int quad = lane >> 4;
    const int l16 = lane & 15;

    const int i = blockIdx.x;        // 512 blocks
    const int ks = i & 3;
    const int m_blk = (i >> 2) & 1;
    const int n_blk = i >> 3;        // 0..63
    const int gm0 = m_blk * BM;
    const int gn0 = n_blk * BN;
    const int kt0 = ks * KITER;
    const int n_id0 = n_blk * 4;     // 4 hash tiles per block

    if (tid < KITER * 4) {
        int kp = tid >> 2, tile = tid & 3;
        Ss[tid] = starts[(kt0 + kp) * NT + n_id0 + tile];
    }

    // ---- A staging via global_load_lds: wave t covers rows t*16..t*16+15 per instr ----
    const int a_t = wave * 2;                              // first of this wave's 2 instrs
    const int a_chunk = (lane & 3) ^ ((lane >> 3) & 3);    // swizzled global chunk
    const __half* a_g0 = xh + (size_t)(gm0 + a_t * 16 + (lane >> 2)) * KDIM
                         + kt0 * 32 + a_chunk * 8;
    const __half* a_g1 = a_g0 + (size_t)16 * KDIM;         // rows +16

#define STAGE_A(c_, kp_) do {                                                  \
        gload16(a_g0 + (kp_) * 32, &As[c_][a_t * 512]);                        \
        gload16(a_g1 + (kp_) * 32, &As[c_][a_t * 512 + 512]);                  \
    } while (0)

    // ---- B staging (reg-staged pack, swizzled; R6-verbatim data path) ----
    const int b_tile = tid >> 7;              // 0..3
    const int t7 = tid & 127;
    const int b_np = t7 & 15;                 // n-pair
    const int b_kg = t7 >> 4;                 // 0..7 : 4-k group
    const int b_oct = b_kg >> 1;
    const unsigned b_base = b_oct * BSLAB;
    const unsigned b_pos = (b_tile * 32 + 2 * b_np) * 8 + (b_kg & 1) * 4;
    const unsigned bswz = (b_np & 4) << 1;    // = (n_even & 8)

    unsigned pbA0, pbA1, pbA2, pbA3, pbB0, pbB1, pbB2, pbB3;

#define LOADT(Q0, Q1, Q2, Q3, kp_) do {                                        \
        int st = Ss[(kp_) * 4 + b_tile];                                       \
        const __half* src = hh + st + b_kg * 128 + b_np * 2;                   \
        Q0 = *(const unsigned*)(src);                                          \
        Q1 = *(const unsigned*)(src + 32);                                     \
        Q2 = *(const unsigned*)(src + 64);                                     \
        Q3 = *(const unsigned*)(src + 96);                                     \
    } while (0)

#define STORET(Q0, Q1, Q2, Q3, c_) do {                                        \
        unsigned lo0 = (Q0 & 0xffffu) | (Q1 << 16);                            \
        unsigned lo1 = (Q2 & 0xffffu) | (Q3 << 16);                            \
        unsigned hi0 = (Q0 >> 16) | (Q1 & 0xffff0000u);                        \
        unsigned hi1 = (Q2 >> 16) | (Q3 & 0xffff0000u);                        \
        uint2 e = {lo0, lo1}, o = {hi0, hi1};                                  \
        *(uint2*)&Bs[c_][b_base + (b_pos ^ bswz)] = e;                         \
        *(uint2*)&Bs[c_][b_base + ((b_pos + 8) ^ bswz)] = o;                   \
    } while (0)

    floatx4 acc[4][4];
#pragma unroll
    for (int r = 0; r < 4; r++)
#pragma unroll
        for (int c = 0; c < 4; c++)
            acc[r][c] = (floatx4){0.f, 0.f, 0.f, 0.f};

    const unsigned rswz = (unsigned)(l16 & 8);          // B read swizzle
    const unsigned a_rswz = (unsigned)((l16 >> 1) & 3); // A read chunk swizzle

    half8 fa0, fa1, fa2, fa3, fb0, fb1, fb2, fb3;

#define READF(c_) do {                                                         \
        fa0 = *(const half8*)&As[c_][(unsigned)(wm * 64 +  0 + l16) * 32 + ((quad ^ a_rswz) * 8)]; \
        fa1 = *(const half8*)&As[c_][(unsigned)(wm * 64 + 16 + l16) * 32 + ((quad ^ a_rswz) * 8)]; \
        fa2 = *(const half8*)&As[c_][(unsigned)(wm * 64 + 32 + l16) * 32 + ((quad ^ a_rswz) * 8)]; \
        fa3 = *(const half8*)&As[c_][(unsigned)(wm * 64 + 48 + l16) * 32 + ((quad ^ a_rswz) * 8)]; \
        fb0 = *(const half8*)&Bs[c_][quad * BSLAB + ((unsigned)((wn * 64 +  0 + l16) * 8) ^ rswz)]; \
        fb1 = *(const half8*)&Bs[c_][quad * BSLAB + ((unsigned)((wn * 64 + 16 + l16) * 8) ^ rswz)]; \
        fb2 = *(const half8*)&Bs[c_][quad * BSLAB + ((unsigned)((wn * 64 + 32 + l16) * 8) ^ rswz)]; \
        fb3 = *(const half8*)&Bs[c_][quad * BSLAB + ((unsigned)((wn * 64 + 48 + l16) * 8) ^ rswz)]; \
    } while (0)

#define MFMAC() do {                                                           \
        __builtin_amdgcn_s_setprio(1);                                         \
        acc[0][0] = __builtin_amdgcn_mfma_f32_16x16x32_f16(fa0, fb0, acc[0][0], 0, 0, 0); \
        acc[1][0] = __builtin_amdgcn_mfma_f32_16x16x32_f16(fa1, fb0, acc[1][0], 0, 0, 0); \
        acc[2][0] = __builtin_amdgcn_mfma_f32_16x16x32_f16(fa2, fb0, acc[2][0], 0, 0, 0); \
        acc[3][0] = __builtin_amdgcn_mfma_f32_16x16x32_f16(fa3, fb0, acc[3][0], 0, 0, 0); \
        acc[0][1] = __builtin_amdgcn_mfma_f32_16x16x32_f16(fa0, fb1, acc[0][1], 0, 0, 0); \
        acc[1][1] = __builtin_amdgcn_mfma_f32_16x16x32_f16(fa1, fb1, acc[1][1], 0, 0, 0); \
        acc[2][1] = __builtin_amdgcn_mfma_f32_16x16x32_f16(fa2, fb1, acc[2][1], 0, 0, 0); \
        acc[3][1] = __builtin_amdgcn_mfma_f32_16x16x32_f16(fa3, fb1, acc[3][1], 0, 0, 0); \
        acc[0][2] = __builtin_amdgcn_mfma_f32_16x16x32_f16(fa0, fb2, acc[0][2], 0, 0, 0); \
        acc[1][2] = __builtin_amdgcn_mfma_f32_16x16x32_f16(fa1, fb2, acc[1][2], 0, 0, 0); \
        acc[2][2] = __builtin_amdgcn_mfma_f32_16x16x32_f16(fa2, fb2, acc[2][2], 0, 0, 0); \
        acc[3][2] = __builtin_amdgcn_mfma_f32_16x16x32_f16(fa3, fb2, acc[3][2], 0, 0, 0); \
        acc[0][3] = __builtin_amdgcn_mfma_f32_16x16x32_f16(fa0, fb3, acc[0][3], 0, 0, 0); \
        acc[1][3] = __builtin_amdgcn_mfma_f32_16x16x32_f16(fa1, fb3, acc[1][3], 0, 0, 0); \
        acc[2][3] = __builtin_amdgcn_mfma_f32_16x16x32_f16(fa2, fb3, acc[2][3], 0, 0, 0); \
        acc[3][3] = __builtin_amdgcn_mfma_f32_16x16x32_f16(fa3, fb3, acc[3][3], 0, 0, 0); \
        __builtin_amdgcn_s_setprio(0);                                         \
    } while (0)

// One phase, one barrier. bR=read buf (tile t), bS=stage buf (tile t+2);
// QL=set loaded with tile t+3's B; QS=set holding tile t+2's B (packed here).
// STORET's implicit vmcnt(6) drains this phase's STAGE_A before the next barrier.
#define PHASE(bR, bS, QL0,QL1,QL2,QL3, QS0,QS1,QS2,QS3, t_) do {               \
        READF(bR);                                                             \
        STAGE_A(bS, (t_) + 2);                                                 \
        SBAR();                                                                \
        LOADT(QL0,QL1,QL2,QL3, (t_) + 3);                                      \
        SBAR();                                                                \
        WAIT_LGKM0();                                                          \
        __builtin_amdgcn_s_barrier();                                          \
        SBAR();                                                                \
        MFMAC();                                                               \
        STORET(QS0,QS1,QS2,QS3, bS);                                           \
        SBAR();                                                                \
    } while (0)

    // ---- prologue: tiles 0,1 fully staged; tile 2's B in set A ----
    __syncthreads();                  // Ss visible
    STAGE_A(0, 0);
    STAGE_A(1, 1);
    SBAR();
    LOADT(pbA0, pbA1, pbA2, pbA3, 0);
    LOADT(pbB0, pbB1, pbB2, pbB3, 1);
    STORET(pbA0, pbA1, pbA2, pbA3, 0);  // implicit vmcnt(4): drains STAGE_A x2 + LOADT(0)
    SBAR();
    LOADT(pbA0, pbA1, pbA2, pbA3, 2);   // set A free -> tile 2's B
    STORET(pbB0, pbB1, pbB2, pbB3, 1);  // implicit vmcnt(4)
    __syncthreads();                    // full drain

    // ---- main loop: 10 x 6 phases (tiles 0..59), static buffer indices ----
    for (int t = 0; t < 60; t += 6) {
        PHASE(0, 2, pbB0,pbB1,pbB2,pbB3, pbA0,pbA1,pbA2,pbA3, t + 0);
        PHASE(1, 0, pbA0,pbA1,pbA2,pbA3, pbB0,pbB1,pbB2,pbB3, t + 1);
        PHASE(2, 1, pbB0,pbB1,pbB2,pbB3, pbA0,pbA1,pbA2,pbA3, t + 2);
        PHASE(0, 2, pbA0,pbA1,pbA2,pbA3, pbB0,pbB1,pbB2,pbB3, t + 3);
        PHASE(1, 0, pbB0,pbB1,pbB2,pbB3, pbA0,pbA1,pbA2,pbA3, t + 4);
        PHASE(2, 1, pbA0,pbA1,pbA2,pbA3, pbB0,pbB1,pbB2,pbB3, t + 5);
    }

    // ---- tail: phases 60..63 (tiles 60..63) ----
    // p60 (pattern 0): full phase; loads tile 63's B, stores tile 62
    PHASE(0, 2, pbB0,pbB1,pbB2,pbB3, pbA0,pbA1,pbA2,pbA3, 60);
    // p61 (pattern 1, no LOADT: tile 64 doesn't exist); stores tile 63 -> buf0
    READF(1);
    STAGE_A(0, 63);
    SBAR();
    WAIT_LGKM0();
    __builtin_amdgcn_s_barrier();
    SBAR();
    MFMAC();
    STORET(pbB0, pbB1, pbB2, pbB3, 0);   // implicit vmcnt(2): STAGE_A(0,63) stays in flight
    SBAR();
    // p62: must drain STAGE_A(0,63) (no younger loads -> explicit vmcnt(0); R11 lesson)
    READF(2);
    SBAR();
    __builtin_amdgcn_s_waitcnt(0x0070);  // vmcnt(0) lgkmcnt(0)
    __builtin_amdgcn_s_barrier();
    SBAR();
    MFMAC();
    // p63: tile 63 from buf0 (fully staged, drained at p62 barrier)
    READF(0);
    SBAR();
    WAIT_LGKM0();
    __builtin_amdgcn_s_barrier();
    SBAR();
    MFMAC();

    // ---- epilogue: atomic accumulate (C/D layout col=lane&15, row=quad*4+reg) ----
#pragma unroll
    for (int c = 0; c < 4; c++) {
        int col = gn0 + wn * 64 + c * 16 + l16;
#pragma unroll
        for (int r = 0; r < 4; r++) {
            int row0 = gm0 + wm * 64 + r * 16 + quad * 4;
#pragma unroll
            for (int e = 0; e < 4; e++)
                atomicAdd(&out[(size_t)(row0 + e) * NDIM + col], acc[r][c][e]);
        }
    }
#undef LOADT
#undef STORET
#undef READF
#undef MFMAC
#undef STAGE_A
#undef PHASE
}

extern "C" void kernel_launch(void* const* d_in, const int* in_sizes, int n_in,
                              void* d_out, int out_size, void* d_ws, size_t ws_size,
                              hipStream_t stream) {
    const float* x = (const float*)d_in[0];
    const float* hw = (const float*)d_in[1];
    const float* bias = (const float*)d_in[2];
    const int* rn = (const int*)d_in[3];
    float* out = (float*)d_out;

    char* ws = (char*)d_ws;
    __half* xh = (__half*)ws;                          // 8 MB : x as f16
    __half* hh = (__half*)(ws + (8u << 20));           // 8 MB : hashed_weight as f16
    int* starts = (int*)(ws + (16u << 20));            // 256 KB : tile start table

    hipLaunchKernelGGL(prep_kernel, dim3(12544), dim3(256), 0, stream,
                       x, hw, bias, rn, xh, hh, starts, out);
    hipLaunchKernelGGL(gemm_kernel, dim3(512), dim3(512), 0, stream, xh, hh, starts, out);
}

// Round 18
// 175.822 us; speedup vs baseline: 1.1195x; 1.1195x over previous
//
#include <hip/hip_runtime.h>
#include <hip/hip_fp16.h>

#define NDIM 8192
#define KDIM 8192
#define NT 256          // N / 32 hash tiles
#define MOD2 4193281    // HASH_SIZE - 32*32 + 1
#define PRIME 2038074743LL

#define BM 256
#define BN 128
#define BK 32
#define KITER 64        // (KDIM/4)/BK, split-K = 4
#define BSLAB 1032      // halves per k-octet slab (128*8 + 8 pad; phase-balanced)

typedef _Float16 half8 __attribute__((ext_vector_type(8)));
typedef float floatx4 __attribute__((ext_vector_type(4)));

// ---------------- fused prepass: cvt fp32->f16, out=bias, ROBE-Z starts ----------------
__global__ __launch_bounds__(256) void prep_kernel(const float* __restrict__ x,
                                                   const float* __restrict__ hw,
                                                   const float* __restrict__ bias,
                                                   const int* __restrict__ rn,
                                                   __half* __restrict__ xh,
                                                   __half* __restrict__ hh,
                                                   int* __restrict__ starts,
                                                   float* __restrict__ out) {
    int b = blockIdx.x;
    int tid = threadIdx.x;
    if (b < 8192) {                       // cvt: 2M threads x 4 floats
        int i = b * 256 + tid;
        const float4* s; __half2* d; int j;
        if (i < (1 << 20)) { s = (const float4*)x;  d = (__half2*)xh; j = i; }
        else               { s = (const float4*)hw; d = (__half2*)hh; j = i - (1 << 20); }
        float4 v = s[j];
        d[j * 2]     = __floats2half2_rn(v.x, v.y);
        d[j * 2 + 1] = __floats2half2_rn(v.z, v.w);
    } else if (b < 8192 + 4096) {         // init: out = bias (atomic-path targets)
        int i = (b - 8192) * 256 + tid;
        float4 bv = *(const float4*)(bias + ((i & 2047) << 2));
        ((float4*)out)[i] = bv;
    } else {                              // starts: 64K hash tile offsets
        int t = (b - 12288) * 256 + tid;
        bool is64 = (rn[1] == 0 && rn[3] == 0);   // int64 input: words 1,3 are hi-halves
        long long R1 = is64 ? rn[2] : rn[1];
        long long R2 = is64 ? rn[4] : rn[2];
        long long R3 = is64 ? rn[6] : rn[3];
        long long k_id = t >> 8, n_id = t & 255;
        long long v = (k_id * R3 + n_id * R2 + R1) % PRIME;
        starts[t] = (int)(v % MOD2);
    }
}

// ---------------- split-K reduce: out = bias + sum of 4 partial planes ----------------
// out is 4M floats = 1,048,576 float4 -> grid 4096 x 256 (R17 bug: was 16384, 4x OOB)
__global__ __launch_bounds__(256) void reduce_kernel(const float* __restrict__ P,
                                                     const float* __restrict__ bias,
                                                     float* __restrict__ out) {
    int v = blockIdx.x * 256 + threadIdx.x;            // float4 index, 1M total
    float4 b  = ((const float4*)bias)[v & 2047];
    float4 p0 = ((const float4*)P)[v];
    float4 p1 = ((const float4*)(P +  4194304))[v];
    float4 p2 = ((const float4*)(P +  8388608))[v];
    float4 p3 = ((const float4*)(P + 12582912))[v];
    float4 o = { b.x + p0.x + p1.x + p2.x + p3.x,
                 b.y + p0.y + p1.y + p2.y + p3.y,
                 b.z + p0.z + p1.z + p2.z + p3.z,
                 b.w + p0.w + p1.w + p2.w + p3.w };
    ((float4*)out)[v] = o;
}

// async global->LDS, 16B per lane; LDS dest = wave-uniform base + lane*16 (HW)
__device__ __forceinline__ void gload16(const __half* g, __half* l) {
    __builtin_amdgcn_global_load_lds((const __attribute__((address_space(1))) void*)g,
                                     (__attribute__((address_space(3))) void*)l, 16, 0, 0);
}

#define SBAR() __builtin_amdgcn_sched_barrier(0)

// ---------------- main GEMM: R12-verbatim loop (112.5us proven) ----------------
// ONLY change vs R12: epilogue branches on 'mode' — plain-store partials (mode=1,
// tests the atomic-tail theory) vs atomicAdd into out (mode=0, R12-exact fallback).
__global__ __launch_bounds__(512, 4) void gemm_kernel(
    const __half* __restrict__ xh, const __half* __restrict__ hh,
    const int* __restrict__ starts, float* __restrict__ out,
    float* __restrict__ partials, int mode) {
    __shared__ __align__(16) __half As[2][BM * 32];        // [m][k] linear, swizzled chunks
    __shared__ __align__(16) __half Bs[2][4 * BSLAB];      // [k-octet][n][8] k-runs, swizzled
    __shared__ int Ss[KITER * 4];                          // per-block starts table

    const int tid = threadIdx.x;
    const int lane = tid & 63;
    const int wave = tid >> 6;       // 0..7
    const int wm = wave >> 1;        // 0..3 : 64-row strip
    const int wn = wave & 1;         // 0..1 : 64-col strip
    const int quad = lane >> 4;
    const int l16 = lane & 15;

    const int i = blockIdx.x;        // 512 blocks
    const int ks = i & 3;
    const int m_blk = (i >> 2) & 1;
    const int n_blk = i >> 3;        // 0..63
    const int gm0 = m_blk * BM;
    const int gn0 = n_blk * BN;
    const int kt0 = ks * KITER;
    const int n_id0 = n_blk * 4;     // 4 hash tiles per block

    if (tid < KITER * 4) {
        int kp = tid >> 2, tile = tid & 3;
        Ss[tid] = starts[(kt0 + kp) * NT + n_id0 + tile];
    }

    // ---- A staging via global_load_lds: wave t covers rows t*16..t*16+15 per instr ----
    const int a_t = wave * 2;                              // first of this wave's 2 instrs
    const int a_chunk = (lane & 3) ^ ((lane >> 3) & 3);    // swizzled global chunk
    const __half* a_g0 = xh + (size_t)(gm0 + a_t * 16 + (lane >> 2)) * KDIM
                         + kt0 * 32 + a_chunk * 8;
    const __half* a_g1 = a_g0 + (size_t)16 * KDIM;         // rows +16

#define STAGE_A(buf_, kp_) do {                                                \
        gload16(a_g0 + (kp_) * 32, &As[buf_][a_t * 512]);                      \
        gload16(a_g1 + (kp_) * 32, &As[buf_][a_t * 512 + 512]);                \
    } while (0)

    // ---- B staging (reg-staged pack, R6-verbatim) ----
    const int b_tile = tid >> 7;              // 0..3
    const int t7 = tid & 127;
    const int b_np = t7 & 15;                 // n-pair
    const int b_kg = t7 >> 4;                 // 0..7 : 4-k group
    const int b_oct = b_kg >> 1;
    const unsigned b_base = b_oct * BSLAB;
    const unsigned b_pos = (b_tile * 32 + 2 * b_np) * 8 + (b_kg & 1) * 4;
    const unsigned bswz = (b_np & 4) << 1;    // = (n_even & 8)

    unsigned pbA0, pbA1, pbA2, pbA3, pbB0, pbB1, pbB2, pbB3;

#define LOADT(Q0, Q1, Q2, Q3, kp_) do {                                        \
        int st = Ss[(kp_) * 4 + b_tile];                                       \
        const __half* src = hh + st + b_kg * 128 + b_np * 2;                   \
        Q0 = *(const unsigned*)(src);                                          \
        Q1 = *(const unsigned*)(src + 32);                                     \
        Q2 = *(const unsigned*)(src + 64);                                     \
        Q3 = *(const unsigned*)(src + 96);                                     \
    } while (0)

#define STORET(Q0, Q1, Q2, Q3, buf_) do {                                      \
        unsigned lo0 = (Q0 & 0xffffu) | (Q1 << 16);                            \
        unsigned lo1 = (Q2 & 0xffffu) | (Q3 << 16);                            \
        unsigned hi0 = (Q0 >> 16) | (Q1 & 0xffff0000u);                        \
        unsigned hi1 = (Q2 >> 16) | (Q3 & 0xffff0000u);                        \
        uint2 e = {lo0, lo1}, o = {hi0, hi1};                                  \
        *(uint2*)&Bs[buf_][b_base + (b_pos ^ bswz)] = e;                       \
        *(uint2*)&Bs[buf_][b_base + ((b_pos + 8) ^ bswz)] = o;                 \
    } while (0)

    floatx4 acc[4][4];
#pragma unroll
    for (int r = 0; r < 4; r++)
#pragma unroll
        for (int c = 0; c < 4; c++)
            acc[r][c] = (floatx4){0.f, 0.f, 0.f, 0.f};

    const unsigned rswz = (unsigned)(l16 & 8);          // B read swizzle
    const unsigned a_rswz = (unsigned)((l16 >> 1) & 3); // A read chunk swizzle

    half8 fa0, fa1, fa2, fa3, fb0, fb1, fb2, fb3;       // frags live across mid-barrier

#define READF(buf_) do {                                                       \
        fa0 = *(const half8*)&As[buf_][(unsigned)(wm * 64 +  0 + l16) * 32 + ((quad ^ a_rswz) * 8)]; \
        fa1 = *(const half8*)&As[buf_][(unsigned)(wm * 64 + 16 + l16) * 32 + ((quad ^ a_rswz) * 8)]; \
        fa2 = *(const half8*)&As[buf_][(unsigned)(wm * 64 + 32 + l16) * 32 + ((quad ^ a_rswz) * 8)]; \
        fa3 = *(const half8*)&As[buf_][(unsigned)(wm * 64 + 48 + l16) * 32 + ((quad ^ a_rswz) * 8)]; \
        fb0 = *(const half8*)&Bs[buf_][quad * BSLAB + ((unsigned)((wn * 64 +  0 + l16) * 8) ^ rswz)]; \
        fb1 = *(const half8*)&Bs[buf_][quad * BSLAB + ((unsigned)((wn * 64 + 16 + l16) * 8) ^ rswz)]; \
        fb2 = *(const half8*)&Bs[buf_][quad * BSLAB + ((unsigned)((wn * 64 + 32 + l16) * 8) ^ rswz)]; \
        fb3 = *(const half8*)&Bs[buf_][quad * BSLAB + ((unsigned)((wn * 64 + 48 + l16) * 8) ^ rswz)]; \
    } while (0)

#define MFMAC() do {                                                           \
        __builtin_amdgcn_s_setprio(1);                                         \
        acc[0][0] = __builtin_amdgcn_mfma_f32_16x16x32_f16(fa0, fb0, acc[0][0], 0, 0, 0); \
        acc[1][0] = __builtin_amdgcn_mfma_f32_16x16x32_f16(fa1, fb0, acc[1][0], 0, 0, 0); \
        acc[2][0] = __builtin_amdgcn_mfma_f32_16x16x32_f16(fa2, fb0, acc[2][0], 0, 0, 0); \
        acc[3][0] = __builtin_amdgcn_mfma_f32_16x16x32_f16(fa3, fb0, acc[3][0], 0, 0, 0); \
        acc[0][1] = __builtin_amdgcn_mfma_f32_16x16x32_f16(fa0, fb1, acc[0][1], 0, 0, 0); \
        acc[1][1] = __builtin_amdgcn_mfma_f32_16x16x32_f16(fa1, fb1, acc[1][1], 0, 0, 0); \
        acc[2][1] = __builtin_amdgcn_mfma_f32_16x16x32_f16(fa2, fb1, acc[2][1], 0, 0, 0); \
        acc[3][1] = __builtin_amdgcn_mfma_f32_16x16x32_f16(fa3, fb1, acc[3][1], 0, 0, 0); \
        acc[0][2] = __builtin_amdgcn_mfma_f32_16x16x32_f16(fa0, fb2, acc[0][2], 0, 0, 0); \
        acc[1][2] = __builtin_amdgcn_mfma_f32_16x16x32_f16(fa1, fb2, acc[1][2], 0, 0, 0); \
        acc[2][2] = __builtin_amdgcn_mfma_f32_16x16x32_f16(fa2, fb2, acc[2][2], 0, 0, 0); \
        acc[3][2] = __builtin_amdgcn_mfma_f32_16x16x32_f16(fa3, fb2, acc[3][2], 0, 0, 0); \
        acc[0][3] = __builtin_amdgcn_mfma_f32_16x16x32_f16(fa0, fb3, acc[0][3], 0, 0, 0); \
        acc[1][3] = __builtin_amdgcn_mfma_f32_16x16x32_f16(fa1, fb3, acc[1][3], 0, 0, 0); \
        acc[2][3] = __builtin_amdgcn_mfma_f32_16x16x32_f16(fa2, fb3, acc[2][3], 0, 0, 0); \
        acc[3][3] = __builtin_amdgcn_mfma_f32_16x16x32_f16(fa3, fb3, acc[3][3], 0, 0, 0); \
        __builtin_amdgcn_s_setprio(0);                                         \
    } while (0)

    __syncthreads();                  // Ss visible (full drain, once)
    STAGE_A(0, 0);                    // A tile 0 -> buf0 (async, 2 gloads)
    LOADT(pbA0, pbA1, pbA2, pbA3, 0); // B tile 0 -> set A
    LOADT(pbB0, pbB1, pbB2, pbB3, 1); // B tile 1 -> set B
    STORET(pbA0, pbA1, pbA2, pbA3, 0);  // implicit vmcnt wait covers A-gloads too
    __syncthreads();                  // tile 0 fully staged

    for (int kp = 0; kp < KITER; kp += 2) {
        // ---- phase even: tile kp (buf0) ----
        READF(0);                                   // 8 ds_reads issued
        STAGE_A(1, kp + 1);                         // A tile kp+1 -> buf1
        if (kp + 2 < KITER) LOADT(pbA0, pbA1, pbA2, pbA3, kp + 2);
        SBAR();
        __builtin_amdgcn_s_barrier();               // rendezvous: hide read latency
        SBAR();
        MFMAC();                                    // compiler inserts lgkmcnt before use
        STORET(pbB0, pbB1, pbB2, pbB3, 1);          // B tile kp+1 -> buf1
        SBAR();
        if (kp + 2 < KITER)
            __builtin_amdgcn_s_waitcnt(0x0074);     // vmcnt(4): drains STAGE_A, pbA in flight
        else
            __builtin_amdgcn_s_waitcnt(0x0070);     // TAIL: vmcnt(0) (R11 race fix)
        __builtin_amdgcn_s_barrier();
        SBAR();

        // ---- phase odd: tile kp+1 (buf1) ----
        READF(1);
        if (kp + 2 < KITER) STAGE_A(0, kp + 2);
        if (kp + 3 < KITER) LOADT(pbB0, pbB1, pbB2, pbB3, kp + 3);
        SBAR();
        __builtin_amdgcn_s_barrier();
        SBAR();
        MFMAC();
        if (kp + 2 < KITER)
            STORET(pbA0, pbA1, pbA2, pbA3, 0);      // B tile kp+2 -> buf0
        SBAR();
        __builtin_amdgcn_s_waitcnt(0x0074);         // vmcnt(4) lgkmcnt(0)
        __builtin_amdgcn_s_barrier();
        SBAR();
    }

    // ---- epilogue: partials plain-store (mode=1) or atomic accumulate (mode=0) ----
    if (mode) {
        float* P = partials + (size_t)ks * (512u * NDIM);   // 16 MB plane per ks
#pragma unroll
        for (int c = 0; c < 4; c++) {
            int col = gn0 + wn * 64 + c * 16 + l16;
#pragma unroll
            for (int r = 0; r < 4; r++) {
                int row0 = gm0 + wm * 64 + r * 16 + quad * 4;
#pragma unroll
                for (int e = 0; e < 4; e++)
                    P[(size_t)(row0 + e) * NDIM + col] = acc[r][c][e];
            }
        }
    } else {
#pragma unroll
        for (int c = 0; c < 4; c++) {
            int col = gn0 + wn * 64 + c * 16 + l16;
#pragma unroll
            for (int r = 0; r < 4; r++) {
                int row0 = gm0 + wm * 64 + r * 16 + quad * 4;
#pragma unroll
                for (int e = 0; e < 4; e++)
                    atomicAdd(&out[(size_t)(row0 + e) * NDIM + col], acc[r][c][e]);
            }
        }
    }
#undef LOADT
#undef STORET
#undef READF
#undef MFMAC
#undef STAGE_A
}

extern "C" void kernel_launch(void* const* d_in, const int* in_sizes, int n_in,
                              void* d_out, int out_size, void* d_ws, size_t ws_size,
                              hipStream_t stream) {
    const float* x = (const float*)d_in[0];
    const float* hw = (const float*)d_in[1];
    const float* bias = (const float*)d_in[2];
    const int* rn = (const int*)d_in[3];
    float* out = (float*)d_out;

    char* ws = (char*)d_ws;
    __half* xh = (__half*)ws;                          // 8 MB : x as f16
    __half* hh = (__half*)(ws + (8u << 20));           // 8 MB : hashed_weight as f16
    int* starts = (int*)(ws + (16u << 20));            // 256 KB : tile start table
    float* partials = (float*)(ws + ((size_t)17 << 20)); // 64 MB : 4 x 16MB ks-planes

    // mode 1 (partials + reduce) only if workspace holds 17MB + 64MB
    int mode = (ws_size >= ((size_t)81 << 20)) ? 1 : 0;

    hipLaunchKernelGGL(prep_kernel, dim3(12544), dim3(256), 0, stream,
                       x, hw, bias, rn, xh, hh, starts, out);
    hipLaunchKernelGGL(gemm_kernel, dim3(512), dim3(512), 0, stream,
                       xh, hh, starts, out, partials, mode);
    if (mode)
        hipLaunchKernelGGL(reduce_kernel, dim3(4096), dim3(256), 0, stream,
                           partials, bias, out);
}